// Round 7
// baseline (351201.392 us; speedup 1.0000x reference)
//
#include <hip/hip_runtime.h>
#include <math.h>

// 2-layer GRU, T=4096, B=64, H=512, input=1. Output = final hidden (2,64,512) f32.
//
// R7: persistent, fence-free (relaxed agent atomics via LLC, proven R6), plus:
//  - software-pipelined LLC h-loads: ping-pong 32-register chunks, next chunk
//    issued before current chunk's FMAs (one latency exposed per step)
//  - decoupled flags (no master/epoch): per-WG iteration flag; wave0 gathers
//    needed flags with slack from depth-4 rings:
//      L0@t waits L0min>=t && L1min>=t-3 ; L1@t waits L0min>=t && L1min>=t-1
//    own flag excluded from the poll.
//   L0: WGs [0,64):  8 j per WG, wave w: k in [w*128,(w+1)*128)
//   L1: WGs [64,192): 4 j per WG, wave w: k in [w*256,(w+1)*256) of K=1024
// Rings: h state s lives in slot s&3. ws: hT0[4][512][64] | hT1[4][512][64]
// | flags[192*32 u32]

#define TT 4096
#define BB 64
#define HH 512
#define HB (HH * BB)
#define NWG 192
#define L0WG 64
#define PADU 32

__device__ __forceinline__ float sigm(float v) { return 1.0f / (1.0f + expf(-v)); }

__device__ __forceinline__ float aldf(const float* p) {
    return __hip_atomic_load((float*)p, __ATOMIC_RELAXED, __HIP_MEMORY_SCOPE_AGENT);
}
__device__ __forceinline__ void astf(float* p, float v) {
    __hip_atomic_store(p, v, __ATOMIC_RELAXED, __HIP_MEMORY_SCOPE_AGENT);
}
__device__ __forceinline__ unsigned aldu(const unsigned* p) {
    return __hip_atomic_load((unsigned*)p, __ATOMIC_RELAXED, __HIP_MEMORY_SCOPE_AGENT);
}
__device__ __forceinline__ void astu(unsigned* p, unsigned v) {
    __hip_atomic_store(p, v, __ATOMIC_RELAXED, __HIP_MEMORY_SCOPE_AGENT);
}

__global__ __launch_bounds__(256) void zero_k(float* p, int n) {
    int i = blockIdx.x * 256 + threadIdx.x;
    if (i < n) p[i] = 0.0f;
}

// wave0 polls: group0 (L0 flags, need0), groups 1-2 (L1 flags, need1).
// Own flag excluded (own store may still be in flight at LLC).
__device__ __forceinline__ void wait_flags(unsigned* flags, int tid, int id,
                                           unsigned need0, unsigned need1) {
    if (tid < 64) {
        for (;;) {
            unsigned a = aldu(&flags[tid * PADU]);
            unsigned b = aldu(&flags[(64 + tid) * PADU]);
            unsigned c = aldu(&flags[(128 + tid) * PADU]);
            bool oka = (tid == id)       || (a >= need0);
            bool okb = (64 + tid == id)  || (b >= need1);
            bool okc = (128 + tid == id) || (c >= need1);
            if (__all(oka && okb && okc)) break;
            __builtin_amdgcn_s_sleep(1);
        }
    }
    __syncthreads();
    asm volatile("" ::: "memory");
}

__global__ __launch_bounds__(256) void gru_persist(
    const float* __restrict__ x,
    const float* __restrict__ wih0, const float* __restrict__ whh0,
    const float* __restrict__ bih0, const float* __restrict__ bhh0,
    const float* __restrict__ wih1, const float* __restrict__ whh1,
    const float* __restrict__ bih1, const float* __restrict__ bhh1,
    float* __restrict__ ws)
{
    __shared__ float wlds[12288];   // 48 KB weights
    __shared__ float red[3072];     // 12 KB cross-wave reduction

    float* hT0 = ws;                         // [4][512][64]
    float* hT1 = ws + 4 * HB;                // [4][512][64]
    unsigned* flags = (unsigned*)(ws + 8 * HB);

    const int tid  = threadIdx.x;
    const int lane = tid & 63;               // batch index b
    const int w    = tid >> 6;               // wave 0..3
    const int id   = blockIdx.x;

    if (id < L0WG) {
        // ===================== Layer 0 =====================
        const int jg = id;
        for (int idx = tid; idx < 24 * 512; idx += 256) {
            int e = idx >> 9, k = idx & 511;
            int jl = e / 3, g = e - 3 * jl;
            wlds[k * 24 + e] = whh0[(size_t)(g * HH + jg * 8 + jl) * HH + k];
        }
        const int ja = jg * 8 + 2 * w, jb = ja + 1;
        const float wirA = wih0[ja], wizA = wih0[HH + ja], winA = wih0[2 * HH + ja];
        const float wirB = wih0[jb], wizB = wih0[HH + jb], winB = wih0[2 * HH + jb];
        const float brA = bih0[ja] + bhh0[ja];
        const float bzA = bih0[HH + ja] + bhh0[HH + ja];
        const float bnxA = bih0[2 * HH + ja], bnhA = bhh0[2 * HH + ja];
        const float brB = bih0[jb] + bhh0[jb];
        const float bzB = bih0[HH + jb] + bhh0[HH + jb];
        const float bnxB = bih0[2 * HH + jb], bnhB = bhh0[2 * HH + jb];
        const int kb = w * 128;
        __syncthreads();

        for (int t = 0; t < TT; ++t) {
            if (t >= 1) {
                unsigned need1 = (t >= 3) ? (unsigned)(t - 3) : 0u;
                wait_flags(flags, tid, id, (unsigned)t, need1);
            }
            const float* hin  = hT0 + ((t + 3) & 3) * HB;   // state t-1
            float*       hout = hT0 + (t & 3) * HB;         // state t
            const float* hbase = hin + lane;

            float hA[32], hB[32];
            #pragma unroll
            for (int i = 0; i < 32; ++i) hA[i] = aldf(hbase + (kb + i) * 64);
            float acc[24];
            #pragma unroll
            for (int e = 0; e < 24; ++e) acc[e] = 0.0f;

            #pragma unroll 1
            for (int c = 0; c < 2; ++c) {
                const int k0 = kb + c * 64;
                #pragma unroll
                for (int i = 0; i < 32; ++i) hB[i] = aldf(hbase + (k0 + 32 + i) * 64);
                #pragma unroll
                for (int i = 0; i < 32; ++i) {
                    const float hv = hA[i];
                    const float4* wp = (const float4*)&wlds[(k0 + i) * 24];
                    const float4 q0 = wp[0], q1 = wp[1], q2 = wp[2];
                    const float4 q3 = wp[3], q4 = wp[4], q5 = wp[5];
                    acc[0] += q0.x * hv; acc[1] += q0.y * hv; acc[2] += q0.z * hv; acc[3] += q0.w * hv;
                    acc[4] += q1.x * hv; acc[5] += q1.y * hv; acc[6] += q1.z * hv; acc[7] += q1.w * hv;
                    acc[8] += q2.x * hv; acc[9] += q2.y * hv; acc[10] += q2.z * hv; acc[11] += q2.w * hv;
                    acc[12] += q3.x * hv; acc[13] += q3.y * hv; acc[14] += q3.z * hv; acc[15] += q3.w * hv;
                    acc[16] += q4.x * hv; acc[17] += q4.y * hv; acc[18] += q4.z * hv; acc[19] += q4.w * hv;
                    acc[20] += q5.x * hv; acc[21] += q5.y * hv; acc[22] += q5.z * hv; acc[23] += q5.w * hv;
                }
                if (c < 1) {
                    #pragma unroll
                    for (int i = 0; i < 32; ++i) hA[i] = aldf(hbase + (k0 + 64 + i) * 64);
                }
                #pragma unroll
                for (int i = 0; i < 32; ++i) {
                    const float hv = hB[i];
                    const float4* wp = (const float4*)&wlds[(k0 + 32 + i) * 24];
                    const float4 q0 = wp[0], q1 = wp[1], q2 = wp[2];
                    const float4 q3 = wp[3], q4 = wp[4], q5 = wp[5];
                    acc[0] += q0.x * hv; acc[1] += q0.y * hv; acc[2] += q0.z * hv; acc[3] += q0.w * hv;
                    acc[4] += q1.x * hv; acc[5] += q1.y * hv; acc[6] += q1.z * hv; acc[7] += q1.w * hv;
                    acc[8] += q2.x * hv; acc[9] += q2.y * hv; acc[10] += q2.z * hv; acc[11] += q2.w * hv;
                    acc[12] += q3.x * hv; acc[13] += q3.y * hv; acc[14] += q3.z * hv; acc[15] += q3.w * hv;
                    acc[16] += q4.x * hv; acc[17] += q4.y * hv; acc[18] += q4.z * hv; acc[19] += q4.w * hv;
                    acc[20] += q5.x * hv; acc[21] += q5.y * hv; acc[22] += q5.z * hv; acc[23] += q5.w * hv;
                }
            }

            // cross-wave reduction, round 1: e 0..11 (jl 0..3)
            float4* r4 = (float4*)red;
            const int rb4 = (w * 64 + lane) * 3;
            r4[rb4 + 0] = make_float4(acc[0], acc[1], acc[2], acc[3]);
            r4[rb4 + 1] = make_float4(acc[4], acc[5], acc[6], acc[7]);
            r4[rb4 + 2] = make_float4(acc[8], acc[9], acc[10], acc[11]);
            __syncthreads();
            float sA0 = 0.f, sA1 = 0.f, sA2 = 0.f, sB0 = 0.f, sB1 = 0.f, sB2 = 0.f;
            if (w < 2) {
                #pragma unroll
                for (int wp_ = 0; wp_ < 4; ++wp_) {
                    const float* rb = &red[(wp_ * 64 + lane) * 12 + 6 * w];
                    sA0 += rb[0]; sA1 += rb[1]; sA2 += rb[2];
                    sB0 += rb[3]; sB1 += rb[4]; sB2 += rb[5];
                }
            }
            __syncthreads();
            // round 2: e 12..23 (jl 4..7)
            r4[rb4 + 0] = make_float4(acc[12], acc[13], acc[14], acc[15]);
            r4[rb4 + 1] = make_float4(acc[16], acc[17], acc[18], acc[19]);
            r4[rb4 + 2] = make_float4(acc[20], acc[21], acc[22], acc[23]);
            __syncthreads();
            if (w >= 2) {
                #pragma unroll
                for (int wp_ = 0; wp_ < 4; ++wp_) {
                    const float* rb = &red[(wp_ * 64 + lane) * 12 + 6 * (w - 2)];
                    sA0 += rb[0]; sA1 += rb[1]; sA2 += rb[2];
                    sB0 += rb[3]; sB1 += rb[4]; sB2 += rb[5];
                }
            }
            // epilogue: 2 outputs per thread
            const float xv = x[(size_t)t * BB + lane];
            const float holdA = aldf(&hin[ja * 64 + lane]);
            const float holdB = aldf(&hin[jb * 64 + lane]);
            {
                const float r = sigm(xv * wirA + brA + sA0);
                const float z = sigm(xv * wizA + bzA + sA1);
                const float n = tanhf(xv * winA + bnxA + r * (sA2 + bnhA));
                astf(&hout[ja * 64 + lane], (1.0f - z) * n + z * holdA);
            }
            {
                const float r = sigm(xv * wirB + brB + sB0);
                const float z = sigm(xv * wizB + bzB + sB1);
                const float n = tanhf(xv * winB + bnxB + r * (sB2 + bnhB));
                astf(&hout[jb * 64 + lane], (1.0f - z) * n + z * holdB);
            }
            __syncthreads();                    // all waves' stores drained
            if (tid == 0) astu(&flags[id * PADU], (unsigned)(t + 1));
        }
    } else {
        // ===================== Layer 1 =====================
        const int jg = id - L0WG;            // 0..127
        for (int idx = tid; idx < 12 * 1024; idx += 256) {
            int e = idx >> 10, k = idx & 1023;
            int jl = e / 3, g = e - 3 * jl;
            int row = g * HH + jg * 4 + jl;
            wlds[k * 12 + e] = (k < HH) ? wih1[(size_t)row * HH + k]
                                        : whh1[(size_t)row * HH + (k - HH)];
        }
        const int j = jg * 4 + w;
        const float br  = bih1[j] + bhh1[j];
        const float bz  = bih1[HH + j] + bhh1[HH + j];
        const float bnx = bih1[2 * HH + j], bnh = bhh1[2 * HH + j];
        const int kb = w * 256;
        __syncthreads();

        for (int t = 1; t <= TT; ++t) {       // computes state t-1
            wait_flags(flags, tid, id, (unsigned)t, (unsigned)(t - 1));
            const float* y0  = hT0 + ((t + 3) & 3) * HB;   // h0 state t-1
            const float* h1i = hT1 + ((t + 2) & 3) * HB;   // h1 state t-2
            float*       h1o = hT1 + ((t + 3) & 3) * HB;   // h1 state t-1
            const float* src = ((w < 2) ? y0 : h1i) + lane;
            const int koff = (w < 2) ? kb : (kb - 512);

            float hA[32], hB[32];
            #pragma unroll
            for (int i = 0; i < 32; ++i) hA[i] = aldf(src + (koff + i) * 64);
            float acc[12];
            #pragma unroll
            for (int e = 0; e < 12; ++e) acc[e] = 0.0f;

            #pragma unroll 1
            for (int c = 0; c < 4; ++c) {
                const int k0 = c * 64;
                #pragma unroll
                for (int i = 0; i < 32; ++i)
                    hB[i] = aldf(src + (koff + k0 + 32 + i) * 64);
                #pragma unroll
                for (int i = 0; i < 32; ++i) {
                    const float hv = hA[i];
                    const float4* wp = (const float4*)&wlds[(kb + k0 + i) * 12];
                    const float4 q0 = wp[0], q1 = wp[1], q2 = wp[2];
                    acc[0] += q0.x * hv; acc[1] += q0.y * hv; acc[2] += q0.z * hv; acc[3] += q0.w * hv;
                    acc[4] += q1.x * hv; acc[5] += q1.y * hv; acc[6] += q1.z * hv; acc[7] += q1.w * hv;
                    acc[8] += q2.x * hv; acc[9] += q2.y * hv; acc[10] += q2.z * hv; acc[11] += q2.w * hv;
                }
                if (c < 3) {
                    #pragma unroll
                    for (int i = 0; i < 32; ++i)
                        hA[i] = aldf(src + (koff + k0 + 64 + i) * 64);
                }
                #pragma unroll
                for (int i = 0; i < 32; ++i) {
                    const float hv = hB[i];
                    const float4* wp = (const float4*)&wlds[(kb + k0 + 32 + i) * 12];
                    const float4 q0 = wp[0], q1 = wp[1], q2 = wp[2];
                    acc[0] += q0.x * hv; acc[1] += q0.y * hv; acc[2] += q0.z * hv; acc[3] += q0.w * hv;
                    acc[4] += q1.x * hv; acc[5] += q1.y * hv; acc[6] += q1.z * hv; acc[7] += q1.w * hv;
                    acc[8] += q2.x * hv; acc[9] += q2.y * hv; acc[10] += q2.z * hv; acc[11] += q2.w * hv;
                }
            }

            // single-round cross-wave reduction
            float4* r4 = (float4*)red;
            const int rb4 = (w * 64 + lane) * 3;
            r4[rb4 + 0] = make_float4(acc[0], acc[1], acc[2], acc[3]);
            r4[rb4 + 1] = make_float4(acc[4], acc[5], acc[6], acc[7]);
            r4[rb4 + 2] = make_float4(acc[8], acc[9], acc[10], acc[11]);
            __syncthreads();
            float sr = 0.f, sz = 0.f, snx = 0.f, snh = 0.f;
            #pragma unroll
            for (int wp_ = 0; wp_ < 4; ++wp_) {
                const float* rb = &red[(wp_ * 64 + lane) * 12 + 3 * w];
                sr += rb[0]; sz += rb[1];
                if (wp_ < 2) snx += rb[2]; else snh += rb[2];
            }
            const float hold = aldf(&h1i[j * 64 + lane]);
            const float r = sigm(sr + br);
            const float z = sigm(sz + bz);
            const float n = tanhf(snx + bnx + r * (snh + bnh));
            astf(&h1o[j * 64 + lane], (1.0f - z) * n + z * hold);
            __syncthreads();                    // stores drained + red safe
            if (tid == 0) astu(&flags[id * PADU], (unsigned)t);
        }
    }
}

// out[l][b][j] = hTl[slot 3][j][b]  (state 4095, slot 4095&3 = 3)
__global__ __launch_bounds__(256) void copy_out_k(const float* __restrict__ ws,
                                                  float* __restrict__ out) {
    int i = blockIdx.x * 256 + threadIdx.x;
    int l = i >> 15;
    int r = i & 32767;
    int b = r >> 9;
    int j = r & 511;
    out[i] = ws[(size_t)l * 4 * HB + 3 * HB + j * 64 + b];
}

extern "C" void kernel_launch(void* const* d_in, const int* in_sizes, int n_in,
                              void* d_out, int out_size, void* d_ws, size_t ws_size,
                              hipStream_t stream)
{
    const float* x    = (const float*)d_in[0];
    const float* wih0 = (const float*)d_in[1];
    const float* whh0 = (const float*)d_in[2];
    const float* bih0 = (const float*)d_in[3];
    const float* bhh0 = (const float*)d_in[4];
    const float* wih1 = (const float*)d_in[5];
    const float* whh1 = (const float*)d_in[6];
    const float* bih1 = (const float*)d_in[7];
    const float* bhh1 = (const float*)d_in[8];
    float* out = (float*)d_out;
    float* ws  = (float*)d_ws;

    const int nzero = 8 * HB + NWG * PADU;   // rings (4-deep x2) + flags
    zero_k<<<(nzero + 255) / 256, 256, 0, stream>>>(ws, nzero);
    gru_persist<<<NWG, 256, 0, stream>>>(x, wih0, whh0, bih0, bhh0,
                                         wih1, whh1, bih1, bhh1, ws);
    copy_out_k<<<(2 * BB * HH) / 256, 256, 0, stream>>>(ws, out);
}